// Round 1
// baseline (416.074 us; speedup 1.0000x reference)
//
#include <hip/hip_runtime.h>

// GCN 2-layer for MI355X (gfx950), fp32.
// Pipeline per call (deterministic work, all on `stream`):
//   1. cnt[v]   = #incoming edges (atomicAdd int)
//   2. rowstart = exclusive scan(cnt)  (single 1024-thread block), dinv[v]=rsqrt(cnt+1)
//   3. csr_src  = sources grouped by dst (fill with atomic slot counters)
//   4. g1 = dinv .* (x @ W1)            tiled LDS GEMM, epilogue scale
//   5. h2 = relu(dinv .* (g1[v] + sum_{u->v} g1[u]) + b1)   gather per node
//   6. g2 = dinv .* (h2 @ W2)
//   7. out = relu(dinv .* (g2[v] + sum g2[u]) + b2)

#define K_DIM 128   // inner dim of both GEMMs (d_in = h_dim = 128)

__global__ void count_edges_kernel(const int* __restrict__ dst, int e, int* __restrict__ cnt) {
    int i = blockIdx.x * blockDim.x + threadIdx.x;
    if (i < e) atomicAdd(&cnt[dst[i]], 1);
}

// Single-block exclusive scan over n<=~64k counts; also emits dinv.
__global__ __launch_bounds__(1024) void scan_kernel(const int* __restrict__ cnt, int n,
                                                    int* __restrict__ rowstart,
                                                    float* __restrict__ dinv) {
    __shared__ int sums[1024];
    int t = threadIdx.x;
    int chunk = (n + 1023) / 1024;
    int lo = t * chunk;
    int hi = min(lo + chunk, n);
    int s = 0;
    for (int i = lo; i < hi; ++i) s += cnt[i];
    sums[t] = s;
    __syncthreads();
    // Hillis-Steele inclusive scan
    for (int off = 1; off < 1024; off <<= 1) {
        int v = (t >= off) ? sums[t - off] : 0;
        __syncthreads();
        sums[t] += v;
        __syncthreads();
    }
    int base = (t == 0) ? 0 : sums[t - 1];
    for (int i = lo; i < hi; ++i) {
        int c = cnt[i];
        rowstart[i] = base;
        base += c;
        dinv[i] = rsqrtf((float)(c + 1));   // +1 = self loop; deg always >= 1
    }
    if (t == 1023) rowstart[n] = sums[1023];
}

__global__ void fill_csr_kernel(const int* __restrict__ src, const int* __restrict__ dst, int e,
                                const int* __restrict__ rowstart, int* __restrict__ slot,
                                int* __restrict__ csr_src) {
    int i = blockIdx.x * blockDim.x + threadIdx.x;
    if (i < e) {
        int d = dst[i];
        int j = rowstart[d] + atomicAdd(&slot[d], 1);
        csr_src[j] = src[i];
    }
}

// C[n,COLS] = dinv[row] * (A[n,128] @ W[128,COLS]).  64-row tiles, A staged in LDS,
// W streamed from global (64KB, shared by all blocks -> L1/L2 resident).
template <int COLS>
__global__ __launch_bounds__(256) void gemm_scale_kernel(const float* __restrict__ A,
                                                         const float* __restrict__ W,
                                                         const float* __restrict__ dinv,
                                                         float* __restrict__ out, int n) {
    constexpr int CG  = COLS / 4;   // col groups (float4 each)
    constexpr int RG  = 256 / CG;   // row groups
    constexpr int RPT = 64 / RG;    // rows per thread
    __shared__ float Asl[64][132];  // stride 132: 16B-aligned rows, <=2-way bank alias
    int t    = threadIdx.x;
    int row0 = blockIdx.x * 64;

    // stage A tile: 64x128 floats, 256 threads x float4 x 8 iters
    #pragma unroll
    for (int it = 0; it < 8; ++it) {
        int idx = (it * 256 + t) * 4;
        int r = idx >> 7;
        int k = idx & 127;
        int gr = row0 + r;
        float4 v = {0.f, 0.f, 0.f, 0.f};
        if (gr < n) v = *(const float4*)&A[gr * K_DIM + k];
        *(float4*)&Asl[r][k] = v;
    }
    __syncthreads();

    int cg = t % CG, rg = t / CG;
    int c0 = cg * 4;
    float acc[RPT][4];
    #pragma unroll
    for (int i = 0; i < RPT; ++i)
        for (int j = 0; j < 4; ++j) acc[i][j] = 0.f;

    for (int k = 0; k < K_DIM; ++k) {
        float4 w = *(const float4*)&W[k * COLS + c0];
        #pragma unroll
        for (int i = 0; i < RPT; ++i) {
            float a = Asl[rg * RPT + i][k];
            acc[i][0] = fmaf(a, w.x, acc[i][0]);
            acc[i][1] = fmaf(a, w.y, acc[i][1]);
            acc[i][2] = fmaf(a, w.z, acc[i][2]);
            acc[i][3] = fmaf(a, w.w, acc[i][3]);
        }
    }

    #pragma unroll
    for (int i = 0; i < RPT; ++i) {
        int r = row0 + rg * RPT + i;
        if (r < n) {
            float s = dinv[r];
            float4 o = {acc[i][0] * s, acc[i][1] * s, acc[i][2] * s, acc[i][3] * s};
            *(float4*)&out[r * COLS + c0] = o;
        }
    }
}

// One wave per node, lane covers 2 features (128 cols).
__global__ __launch_bounds__(256) void aggregate128_kernel(const float* __restrict__ g,
                                                           const int* __restrict__ rowstart,
                                                           const int* __restrict__ csr_src,
                                                           const float* __restrict__ dinv,
                                                           const float* __restrict__ bias,
                                                           float* __restrict__ out, int n) {
    int wave = threadIdx.x >> 6;
    int lane = threadIdx.x & 63;
    int v = blockIdx.x * 4 + wave;
    if (v >= n) return;
    int s = rowstart[v], epos = rowstart[v + 1];
    float2 acc = *(const float2*)&g[(size_t)v * 128 + lane * 2];   // self loop
    for (int j = s; j < epos; ++j) {
        int u = csr_src[j];                                        // wave-uniform -> s_load
        float2 m = *(const float2*)&g[(size_t)u * 128 + lane * 2];
        acc.x += m.x; acc.y += m.y;
    }
    float dv = dinv[v];
    float2 b = *(const float2*)&bias[lane * 2];
    float2 o = {fmaxf(fmaf(acc.x, dv, b.x), 0.f), fmaxf(fmaf(acc.y, dv, b.y), 0.f)};
    *(float2*)&out[(size_t)v * 128 + lane * 2] = o;
}

// One wave per node, lane covers 1 feature (64 cols).
__global__ __launch_bounds__(256) void aggregate64_kernel(const float* __restrict__ g,
                                                          const int* __restrict__ rowstart,
                                                          const int* __restrict__ csr_src,
                                                          const float* __restrict__ dinv,
                                                          const float* __restrict__ bias,
                                                          float* __restrict__ out, int n) {
    int wave = threadIdx.x >> 6;
    int lane = threadIdx.x & 63;
    int v = blockIdx.x * 4 + wave;
    if (v >= n) return;
    int s = rowstart[v], epos = rowstart[v + 1];
    float acc = g[(size_t)v * 64 + lane];
    for (int j = s; j < epos; ++j) {
        int u = csr_src[j];
        acc += g[(size_t)u * 64 + lane];
    }
    float o = fmaxf(fmaf(acc, dinv[v], bias[lane]), 0.f);
    out[(size_t)v * 64 + lane] = o;
}

extern "C" void kernel_launch(void* const* d_in, const int* in_sizes, int n_in,
                              void* d_out, int out_size, void* d_ws, size_t ws_size,
                              hipStream_t stream) {
    const float* x  = (const float*)d_in[0];
    const int*   ei = (const int*)d_in[1];   // [2, E] int32
    const float* W1 = (const float*)d_in[2];
    const float* b1 = (const float*)d_in[3];
    const float* W2 = (const float*)d_in[4];
    const float* b2 = (const float*)d_in[5];
    float* out = (float*)d_out;

    const int n = in_sizes[0] / 128;   // 50000
    const int e = in_sizes[1] / 2;     // 800000
    const int* src = ei;
    const int* dst = ei + e;

    // workspace carve-up (256B aligned)
    char* ws = (char*)d_ws;
    size_t off = 0;
    auto carve = [&](size_t bytes) -> void* {
        void* p = ws + off;
        off = (off + bytes + 255) & ~(size_t)255;
        return p;
    };
    int*   cnt      = (int*)  carve((size_t)n * 4);
    int*   rowstart = (int*)  carve((size_t)(n + 1) * 4);
    float* dinv     = (float*)carve((size_t)n * 4);
    int*   csr_src  = (int*)  carve((size_t)e * 4);
    float* g1       = (float*)carve((size_t)n * 128 * 4);
    float* h2       = (float*)carve((size_t)n * 128 * 4);
    float* g2       = (float*)carve((size_t)n * 64 * 4);
    (void)ws_size;

    const int eblocks = (e + 255) / 256;

    hipMemsetAsync(cnt, 0, (size_t)n * 4, stream);
    count_edges_kernel<<<eblocks, 256, 0, stream>>>(dst, e, cnt);
    scan_kernel<<<1, 1024, 0, stream>>>(cnt, n, rowstart, dinv);
    hipMemsetAsync(cnt, 0, (size_t)n * 4, stream);   // reuse as fill slots
    fill_csr_kernel<<<eblocks, 256, 0, stream>>>(src, dst, e, rowstart, cnt, csr_src);

    const int gblocks = (n + 63) / 64;
    const int ablocks = (n + 3) / 4;

    // layer 1
    gemm_scale_kernel<128><<<gblocks, 256, 0, stream>>>(x, W1, dinv, g1, n);
    aggregate128_kernel<<<ablocks, 256, 0, stream>>>(g1, rowstart, csr_src, dinv, b1, h2, n);
    // layer 2
    gemm_scale_kernel<64><<<gblocks, 256, 0, stream>>>(h2, W2, dinv, g2, n);
    aggregate64_kernel<<<ablocks, 256, 0, stream>>>(g2, rowstart, csr_src, dinv, b2, out, n);
}

// Round 2
// 241.193 us; speedup vs baseline: 1.7251x; 1.7251x over previous
//
#include <hip/hip_runtime.h>

// GCN 2-layer for MI355X (gfx950), fp32.
// out[v] = relu( dinv[v]*( g[v] + sum_{u->v} g[u] ) + b ),  g = dinv .* (x @ W)
// Pipeline: count -> 3-stage scan (parallel) -> CSR fill -> GEMM+scale -> gather-agg (x2 layers)

#define K_DIM 128

__global__ void count_edges_kernel(const int* __restrict__ dst, int e, int* __restrict__ cnt) {
    int i = blockIdx.x * blockDim.x + threadIdx.x;
    if (i < e) atomicAdd(&cnt[dst[i]], 1);
}

// S1: per-block (1024-elem) sums. 256 threads x int4.
__global__ __launch_bounds__(256) void block_sum_kernel(const int* __restrict__ cnt, int n,
                                                        int* __restrict__ bsum) {
    __shared__ int red[256];
    int t = threadIdx.x;
    int base = blockIdx.x * 1024 + t * 4;
    int s = 0;
    if (base + 3 < n) {
        int4 v = *(const int4*)&cnt[base];
        s = v.x + v.y + v.z + v.w;
    } else {
        for (int i = 0; i < 4; ++i) if (base + i < n) s += cnt[base + i];
    }
    red[t] = s;
    __syncthreads();
    for (int off = 128; off > 0; off >>= 1) {
        if (t < off) red[t] += red[t + off];
        __syncthreads();
    }
    if (t == 0) bsum[blockIdx.x] = red[0];
}

// S2: single-block inclusive scan of nb (<=1024) block sums, in place.
// Thread nb-1 also writes rowstart[n] = total edge count.
__global__ __launch_bounds__(1024) void scan_bsum_kernel(int* __restrict__ bsum, int nb,
                                                         int* __restrict__ rowstart, int n) {
    __shared__ int sh[1024];
    int t = threadIdx.x;
    int v = (t < nb) ? bsum[t] : 0;
    sh[t] = v;
    __syncthreads();
    for (int off = 1; off < 1024; off <<= 1) {
        int w = (t >= off) ? sh[t - off] : 0;
        __syncthreads();
        sh[t] += w;
        __syncthreads();
    }
    if (t < nb) bsum[t] = sh[t];
    if (t == nb - 1) rowstart[n] = sh[t];
}

// S3: local exclusive scan within each 1024-elem block + block offset; emits rowstart + dinv.
__global__ __launch_bounds__(256) void local_scan_kernel(const int* __restrict__ cnt, int n,
                                                         const int* __restrict__ bsum_incl,
                                                         int* __restrict__ rowstart,
                                                         float* __restrict__ dinv) {
    __shared__ int tsum[256];
    int b = blockIdx.x, t = threadIdx.x;
    int base = b * 1024 + t * 4;
    int v[4];
    int s = 0;
    #pragma unroll
    for (int i = 0; i < 4; ++i) {
        int idx = base + i;
        v[i] = (idx < n) ? cnt[idx] : 0;
        s += v[i];
    }
    tsum[t] = s;
    __syncthreads();
    for (int off = 1; off < 256; off <<= 1) {
        int w = (t >= off) ? tsum[t - off] : 0;
        __syncthreads();
        tsum[t] += w;
        __syncthreads();
    }
    int excl = (t == 0 ? 0 : tsum[t - 1]) + (b == 0 ? 0 : bsum_incl[b - 1]);
    #pragma unroll
    for (int i = 0; i < 4; ++i) {
        int idx = base + i;
        if (idx < n) {
            rowstart[idx] = excl;
            excl += v[i];
            dinv[idx] = rsqrtf((float)(v[i] + 1));   // +1 self loop
        }
    }
}

__global__ void fill_csr_kernel(const int* __restrict__ src, const int* __restrict__ dst, int e,
                                const int* __restrict__ rowstart, int* __restrict__ slot,
                                int* __restrict__ csr_src) {
    int i = blockIdx.x * blockDim.x + threadIdx.x;
    if (i < e) {
        int d = dst[i];
        int j = rowstart[d] + atomicAdd(&slot[d], 1);
        csr_src[j] = src[i];
    }
}

// C[n,COLS] = dinv[row] * (A[n,128] @ W[128,COLS]).  64-row tiles, A in LDS, W via L1/L2.
template <int COLS>
__global__ __launch_bounds__(256) void gemm_scale_kernel(const float* __restrict__ A,
                                                         const float* __restrict__ W,
                                                         const float* __restrict__ dinv,
                                                         float* __restrict__ out, int n) {
    constexpr int CG  = COLS / 4;
    constexpr int RG  = 256 / CG;
    constexpr int RPT = 64 / RG;
    __shared__ float Asl[64][132];
    int t    = threadIdx.x;
    int row0 = blockIdx.x * 64;

    #pragma unroll
    for (int it = 0; it < 8; ++it) {
        int idx = (it * 256 + t) * 4;
        int r = idx >> 7;
        int k = idx & 127;
        int gr = row0 + r;
        float4 v = {0.f, 0.f, 0.f, 0.f};
        if (gr < n) v = *(const float4*)&A[gr * K_DIM + k];
        *(float4*)&Asl[r][k] = v;
    }
    __syncthreads();

    int cg = t % CG, rg = t / CG;
    int c0 = cg * 4;
    float acc[RPT][4];
    #pragma unroll
    for (int i = 0; i < RPT; ++i)
        for (int j = 0; j < 4; ++j) acc[i][j] = 0.f;

    for (int k = 0; k < K_DIM; ++k) {
        float4 w = *(const float4*)&W[k * COLS + c0];
        #pragma unroll
        for (int i = 0; i < RPT; ++i) {
            float a = Asl[rg * RPT + i][k];
            acc[i][0] = fmaf(a, w.x, acc[i][0]);
            acc[i][1] = fmaf(a, w.y, acc[i][1]);
            acc[i][2] = fmaf(a, w.z, acc[i][2]);
            acc[i][3] = fmaf(a, w.w, acc[i][3]);
        }
    }

    #pragma unroll
    for (int i = 0; i < RPT; ++i) {
        int r = row0 + rg * RPT + i;
        if (r < n) {
            float s = dinv[r];
            float4 o = {acc[i][0] * s, acc[i][1] * s, acc[i][2] * s, acc[i][3] * s};
            *(float4*)&out[r * COLS + c0] = o;
        }
    }
}

// One wave per node, lane covers 2 features (128 cols). 4x unrolled gather.
__global__ __launch_bounds__(256) void aggregate128_kernel(const float* __restrict__ g,
                                                           const int* __restrict__ rowstart,
                                                           const int* __restrict__ csr_src,
                                                           const float* __restrict__ dinv,
                                                           const float* __restrict__ bias,
                                                           float* __restrict__ out, int n) {
    int wave = threadIdx.x >> 6;
    int lane = threadIdx.x & 63;
    int v = blockIdx.x * 4 + wave;
    if (v >= n) return;
    // bounds are wave-uniform: force into SGPRs so the index loads scalarize
    int s    = __builtin_amdgcn_readfirstlane(rowstart[v]);
    int epos = __builtin_amdgcn_readfirstlane(rowstart[v + 1]);
    int col = lane * 2;
    float2 acc = *(const float2*)&g[(size_t)v * 128 + col];   // self loop
    float2 acc2 = {0.f, 0.f};
    int j = s;
    for (; j + 3 < epos; j += 4) {
        int u0 = csr_src[j], u1 = csr_src[j + 1], u2 = csr_src[j + 2], u3 = csr_src[j + 3];
        float2 m0 = *(const float2*)&g[(size_t)u0 * 128 + col];
        float2 m1 = *(const float2*)&g[(size_t)u1 * 128 + col];
        float2 m2 = *(const float2*)&g[(size_t)u2 * 128 + col];
        float2 m3 = *(const float2*)&g[(size_t)u3 * 128 + col];
        acc.x += m0.x + m1.x; acc.y += m0.y + m1.y;
        acc2.x += m2.x + m3.x; acc2.y += m2.y + m3.y;
    }
    for (; j < epos; ++j) {
        int u = csr_src[j];
        float2 m = *(const float2*)&g[(size_t)u * 128 + col];
        acc.x += m.x; acc.y += m.y;
    }
    acc.x += acc2.x; acc.y += acc2.y;
    float dv = dinv[v];
    float2 b = *(const float2*)&bias[col];
    float2 o = {fmaxf(fmaf(acc.x, dv, b.x), 0.f), fmaxf(fmaf(acc.y, dv, b.y), 0.f)};
    *(float2*)&out[(size_t)v * 128 + col] = o;
}

// One wave per node, lane covers 1 feature (64 cols). 4x unrolled gather.
__global__ __launch_bounds__(256) void aggregate64_kernel(const float* __restrict__ g,
                                                          const int* __restrict__ rowstart,
                                                          const int* __restrict__ csr_src,
                                                          const float* __restrict__ dinv,
                                                          const float* __restrict__ bias,
                                                          float* __restrict__ out, int n) {
    int wave = threadIdx.x >> 6;
    int lane = threadIdx.x & 63;
    int v = blockIdx.x * 4 + wave;
    if (v >= n) return;
    int s    = __builtin_amdgcn_readfirstlane(rowstart[v]);
    int epos = __builtin_amdgcn_readfirstlane(rowstart[v + 1]);
    float acc = g[(size_t)v * 64 + lane];
    float acc2 = 0.f;
    int j = s;
    for (; j + 3 < epos; j += 4) {
        int u0 = csr_src[j], u1 = csr_src[j + 1], u2 = csr_src[j + 2], u3 = csr_src[j + 3];
        float m0 = g[(size_t)u0 * 64 + lane];
        float m1 = g[(size_t)u1 * 64 + lane];
        float m2 = g[(size_t)u2 * 64 + lane];
        float m3 = g[(size_t)u3 * 64 + lane];
        acc += m0 + m1;
        acc2 += m2 + m3;
    }
    for (; j < epos; ++j) {
        int u = csr_src[j];
        acc += g[(size_t)u * 64 + lane];
    }
    acc += acc2;
    float o = fmaxf(fmaf(acc, dinv[v], bias[lane]), 0.f);
    out[(size_t)v * 64 + lane] = o;
}

extern "C" void kernel_launch(void* const* d_in, const int* in_sizes, int n_in,
                              void* d_out, int out_size, void* d_ws, size_t ws_size,
                              hipStream_t stream) {
    const float* x  = (const float*)d_in[0];
    const int*   ei = (const int*)d_in[1];   // [2, E] int32
    const float* W1 = (const float*)d_in[2];
    const float* b1 = (const float*)d_in[3];
    const float* W2 = (const float*)d_in[4];
    const float* b2 = (const float*)d_in[5];
    float* out = (float*)d_out;

    const int n = in_sizes[0] / 128;   // 50000
    const int e = in_sizes[1] / 2;     // 800000
    const int* src = ei;
    const int* dst = ei + e;

    char* ws = (char*)d_ws;
    size_t off = 0;
    auto carve = [&](size_t bytes) -> void* {
        void* p = ws + off;
        off = (off + bytes + 255) & ~(size_t)255;
        return p;
    };
    int*   cnt      = (int*)  carve((size_t)n * 4);
    int*   rowstart = (int*)  carve((size_t)(n + 1) * 4);
    float* dinv     = (float*)carve((size_t)n * 4);
    int*   csr_src  = (int*)  carve((size_t)e * 4);
    int*   bsum     = (int*)  carve((size_t)1024 * 4);
    float* g1       = (float*)carve((size_t)n * 128 * 4);
    float* h2       = (float*)carve((size_t)n * 128 * 4);
    float* g2       = (float*)carve((size_t)n * 64 * 4);
    (void)ws_size;

    const int eblocks = (e + 255) / 256;
    const int nb      = (n + 1023) / 1024;   // scan blocks (49)

    hipMemsetAsync(cnt, 0, (size_t)n * 4, stream);
    count_edges_kernel<<<eblocks, 256, 0, stream>>>(dst, e, cnt);
    block_sum_kernel<<<nb, 256, 0, stream>>>(cnt, n, bsum);
    scan_bsum_kernel<<<1, 1024, 0, stream>>>(bsum, nb, rowstart, n);
    local_scan_kernel<<<nb, 256, 0, stream>>>(cnt, n, bsum, rowstart, dinv);
    hipMemsetAsync(cnt, 0, (size_t)n * 4, stream);   // reuse as fill slots
    fill_csr_kernel<<<eblocks, 256, 0, stream>>>(src, dst, e, rowstart, cnt, csr_src);

    const int gblocks = (n + 63) / 64;
    const int ablocks = (n + 3) / 4;

    gemm_scale_kernel<128><<<gblocks, 256, 0, stream>>>(x, W1, dinv, g1, n);
    aggregate128_kernel<<<ablocks, 256, 0, stream>>>(g1, rowstart, csr_src, dinv, b1, h2, n);
    gemm_scale_kernel<64><<<gblocks, 256, 0, stream>>>(h2, W2, dinv, g2, n);
    aggregate64_kernel<<<ablocks, 256, 0, stream>>>(g2, rowstart, csr_src, dinv, b2, out, n);
}